// Round 1
// baseline (4724.282 us; speedup 1.0000x reference)
//
#include <hip/hip_runtime.h>
#include <stdint.h>

// WindowAttention1D, FULL FP32 pipeline (threshold 2.1e-3 abs at |ref|max≈454
// demands ~1e-6 relative -> no bf16/MFMA; CDNA4 has no fp32 MFMA, so this is
// a vector-FP32 (157.3 TF ceiling) problem).
//
// v2 (theory: QKV GEMM 2.65ms = 59% of total at 49% of fp32 peak, VALUBusy 76%,
// SQ_LDS_BANK_CONFLICT 2.77e8):
//  1. B-fragment reads tx*8 -> {tx*4, 64+tx*4}: wave's ds_read_b128 pair now
//     covers all 32 banks 2-deep (free) instead of 16 banks 4-deep (4-way).
//  2. sAT padded to stride 132: staging scalar writes 4-way -> 2-way (free).
//  3. Double-buffered LDS, ONE barrier per K-step; next tile's global loads
//     issue before the 2048-cycle FMA phase -> HBM latency hidden.
//  4. XCD-chunked block swizzle: blocks sharing an A-panel land on one XCD's
//     L2 (was round-robined over 8 XCDs; FETCH 1.25GB vs 271MB ideal).
//  5. attn: same bF fix in QK^T; Q^T/K^T staging remapped (t lane-fast,
//     stride 132) 16-way -> 2-way writes; V prefetched into regs across an
//     lgkmcnt-only barrier (plain __syncthreads drains vmcnt(0)).

#define SAT_LD 132   // padded leading dim for transposed tiles

// ---------------------------------------------------------------------------
// GEMM: C[M x N] = A[M x K (lda)] @ B[K x N row-major] + bias[N]
// 128x128 tile, BK=16, 256 threads, 8x8 per thread, double-buffered LDS.
// ---------------------------------------------------------------------------
__global__ __launch_bounds__(256) void gemm_f32(
    const float* __restrict__ A, int lda,
    const float* __restrict__ B,
    const float* __restrict__ bias,
    float* __restrict__ C,
    int M, int N, int K)
{
    __shared__ __attribute__((aligned(16))) float sAT[2][16 * SAT_LD];
    __shared__ __attribute__((aligned(16))) float sB[2][16 * 128];

    const int tid = threadIdx.x;
    const int tx = tid & 15;          // n-quad 0..15
    const int ty = tid >> 4;          // m-tile 0..15

    // XCD-chunked bijective swizzle (all our grids have nwg % 8 == 0)
    int bid = blockIdx.y * gridDim.x + blockIdx.x;
    bid = (bid & 7) * ((gridDim.x * gridDim.y) >> 3) + (bid >> 3);
    const long m0 = (long)(bid / gridDim.x) * 128;
    const long n0 = (long)(bid % gridDim.x) * 128;

    float acc[8][8];
#pragma unroll
    for (int i = 0; i < 8; ++i)
#pragma unroll
        for (int j = 0; j < 8; ++j) acc[i][j] = 0.f;

    const int ar = tid >> 2;          // A stage row 0..63
    const int ac = (tid & 3) * 4;     // A stage k-col 0,4,8,12
    const float* Ap0 = A + (m0 + ar) * (long)lda + ac;
    const float* Ap1 = Ap0 + 64 * (long)lda;
    const int bk = tid >> 5;          // B stage k-row 0..7
    const int bc = (tid & 31) * 4;    // B stage col 0..124
    const float* Bp0 = B + (long)bk * N + n0 + bc;
    const float* Bp1 = Bp0 + 8 * (long)N;

    float4 a0 = *(const float4*)Ap0;
    float4 a1 = *(const float4*)Ap1;
    float4 b0 = *(const float4*)Bp0;
    float4 b1 = *(const float4*)Bp1;

#pragma unroll
    for (int j = 0; j < 4; ++j) {
        sAT[0][(ac + j) * SAT_LD + ar]      = ((const float*)&a0)[j];
        sAT[0][(ac + j) * SAT_LD + ar + 64] = ((const float*)&a1)[j];
    }
    *(float4*)&sB[0][bk * 128 + bc]       = b0;
    *(float4*)&sB[0][(bk + 8) * 128 + bc] = b1;
    __syncthreads();

    int cur = 0;
    for (int k0 = 16; k0 < K; k0 += 16) {
        // prefetch next tile (in flight during the compute phase below)
        Ap0 += 16; Ap1 += 16;
        Bp0 += 16 * (long)N; Bp1 += 16 * (long)N;
        a0 = *(const float4*)Ap0;
        a1 = *(const float4*)Ap1;
        b0 = *(const float4*)Bp0;
        b1 = *(const float4*)Bp1;

        const float* sA_ = sAT[cur];
        const float* sB_ = sB[cur];
#pragma unroll
        for (int kk = 0; kk < 16; ++kk) {
            float av[8], bv[8];
            *(float4*)&av[0] = *(const float4*)(sA_ + kk * SAT_LD + ty * 8);
            *(float4*)&av[4] = *(const float4*)(sA_ + kk * SAT_LD + ty * 8 + 4);
            *(float4*)&bv[0] = *(const float4*)(sB_ + kk * 128 + tx * 4);
            *(float4*)&bv[4] = *(const float4*)(sB_ + kk * 128 + 64 + tx * 4);
#pragma unroll
            for (int i = 0; i < 8; ++i)
#pragma unroll
                for (int j = 0; j < 8; ++j)
                    acc[i][j] += av[i] * bv[j];
        }

        // write prefetch into the other buffer; single barrier per K-step
        const int nxt = cur ^ 1;
#pragma unroll
        for (int j = 0; j < 4; ++j) {
            sAT[nxt][(ac + j) * SAT_LD + ar]      = ((const float*)&a0)[j];
            sAT[nxt][(ac + j) * SAT_LD + ar + 64] = ((const float*)&a1)[j];
        }
        *(float4*)&sB[nxt][bk * 128 + bc]       = b0;
        *(float4*)&sB[nxt][(bk + 8) * 128 + bc] = b1;
        __syncthreads();
        cur = nxt;
    }

    // last tile
    {
        const float* sA_ = sAT[cur];
        const float* sB_ = sB[cur];
#pragma unroll
        for (int kk = 0; kk < 16; ++kk) {
            float av[8], bv[8];
            *(float4*)&av[0] = *(const float4*)(sA_ + kk * SAT_LD + ty * 8);
            *(float4*)&av[4] = *(const float4*)(sA_ + kk * SAT_LD + ty * 8 + 4);
            *(float4*)&bv[0] = *(const float4*)(sB_ + kk * 128 + tx * 4);
            *(float4*)&bv[4] = *(const float4*)(sB_ + kk * 128 + 64 + tx * 4);
#pragma unroll
            for (int i = 0; i < 8; ++i)
#pragma unroll
                for (int j = 0; j < 8; ++j)
                    acc[i][j] += av[i] * bv[j];
        }
    }

    const float4 bq0 = *(const float4*)(bias + n0 + tx * 4);
    const float4 bq1 = *(const float4*)(bias + n0 + 64 + tx * 4);
#pragma unroll
    for (int i = 0; i < 8; ++i) {
        const long row = m0 + ty * 8 + i;
        float4 o0 = {acc[i][0] + bq0.x, acc[i][1] + bq0.y,
                     acc[i][2] + bq0.z, acc[i][3] + bq0.w};
        float4 o1 = {acc[i][4] + bq1.x, acc[i][5] + bq1.y,
                     acc[i][6] + bq1.z, acc[i][7] + bq1.w};
        *(float4*)(C + row * (long)N + n0 + tx * 4)      = o0;
        *(float4*)(C + row * (long)N + n0 + 64 + tx * 4) = o1;
    }
}

// ---------------------------------------------------------------------------
// Fused window attention, fp32. One block per (local window bl, head h).
// ---------------------------------------------------------------------------
__global__ __launch_bounds__(256) void attn_f32(
    const float* __restrict__ qkv,
    float* __restrict__ qkv_out,
    const float* __restrict__ mask,
    const float* __restrict__ bt,
    int b_base)
{
    __shared__ __attribute__((aligned(16))) float sQT[64 * SAT_LD]; // later: sV[128][64]
    __shared__ __attribute__((aligned(16))) float sKT[64 * SAT_LD];
    __shared__ __attribute__((aligned(16))) float sS[128 * 129];
    __shared__ float sBias[256];

    const int tid = threadIdx.x;
    int bh = blockIdx.x;
    bh = (bh & 7) * ((int)(gridDim.x) >> 3) + (bh >> 3);   // XCD swizzle
    const int bl = bh >> 3;
    const int h  = bh & 7;
    const int widx = (b_base + bl) & 63;
    const float* base = qkv + (size_t)bl * 128 * 1536 + h * 64;

    // stage Q^T, K^T: token t lane-fast -> LDS writes 2-way (free);
    // global reads are 64B segments per token row.
    {
        const int t_st  = tid & 15;
        const int d4_st = (tid >> 4) * 4;
#pragma unroll
        for (int r = 0; r < 8; ++r) {
            const int t = r * 16 + t_st;
            float4 q = *(const float4*)(base + (size_t)t * 1536 + d4_st);
            float4 k = *(const float4*)(base + (size_t)t * 1536 + 512 + d4_st);
#pragma unroll
            for (int j = 0; j < 4; ++j) {
                sQT[(d4_st + j) * SAT_LD + t] = ((const float*)&q)[j];
                sKT[(d4_st + j) * SAT_LD + t] = ((const float*)&k)[j];
            }
        }
    }
    if (tid < 255) sBias[tid] = bt[tid * 8 + h];
    __syncthreads();

    const int tx = tid & 15;
    const int ty = tid >> 4;

    // ---- S = Q K^T (8 rows x {tx*4, 64+tx*4} cols per thread)
    float acc[8][8];
#pragma unroll
    for (int i = 0; i < 8; ++i)
#pragma unroll
        for (int j = 0; j < 8; ++j) acc[i][j] = 0.f;

    for (int kk = 0; kk < 64; ++kk) {
        float av[8], bv[8];
        *(float4*)&av[0] = *(const float4*)(sQT + kk * SAT_LD + ty * 8);
        *(float4*)&av[4] = *(const float4*)(sQT + kk * SAT_LD + ty * 8 + 4);
        *(float4*)&bv[0] = *(const float4*)(sKT + kk * SAT_LD + tx * 4);
        *(float4*)&bv[4] = *(const float4*)(sKT + kk * SAT_LD + 64 + tx * 4);
#pragma unroll
        for (int i = 0; i < 8; ++i)
#pragma unroll
            for (int j = 0; j < 8; ++j)
                acc[i][j] += av[i] * bv[j];
    }

    // scale + rel-pos bias + mask -> sS (stride 129)
    const float* maskp = mask + (size_t)widx * 16384;
#pragma unroll
    for (int i = 0; i < 8; ++i) {
        const int row = ty * 8 + i;
#pragma unroll
        for (int j = 0; j < 4; ++j) {
            const int c0 = tx * 4 + j;
            const int c1 = 64 + tx * 4 + j;
            sS[row * 129 + c0] = acc[i][j]     * 0.125f + sBias[c0 - row + 127]
                               + maskp[row * 128 + c0];
            sS[row * 129 + c1] = acc[i][j + 4] * 0.125f + sBias[c1 - row + 127]
                               + maskp[row * 128 + c1];
        }
    }

    // V prefetch into regs; stays in flight across the lgkm-only barrier
    float4 vreg[8];
    {
        const float* vbase = base + 1024;
#pragma unroll
        for (int r = 0; r < 8; ++r) {
            const int idx = tid + r * 256;
            vreg[r] = *(const float4*)(vbase + (size_t)(idx >> 4) * 1536
                                       + (idx & 15) * 4);
        }
    }

    // barrier draining LDS only (NOT vmcnt -> V loads keep flying)
    asm volatile("s_waitcnt lgkmcnt(0)" ::: "memory");
    __builtin_amdgcn_s_barrier();

    // ---- softmax: thread pair (tid, tid^1) owns one row (halves of 64)
    {
        const int row = tid >> 1;
        const int hc  = (tid & 1) * 64;
        float* rp = sS + row * 129 + hc;
        float mx = -3.4e38f;
        for (int c = 0; c < 64; ++c) mx = fmaxf(mx, rp[c]);
        mx = fmaxf(mx, __shfl_xor(mx, 1));
        float sum = 0.f;
        for (int c = 0; c < 64; ++c) {
            float e = __expf(rp[c] - mx);
            rp[c] = e;
            sum += e;
        }
        sum += __shfl_xor(sum, 1);
        const float rl = 1.0f / sum;
        for (int c = 0; c < 64; ++c) rp[c] *= rl;
    }

    // write V into the dead sQT region: sV[t][d]
    float* sV = sQT;
#pragma unroll
    for (int r = 0; r < 8; ++r) {
        const int idx = tid + r * 256;
        *(float4*)(sV + (idx >> 4) * 64 + (idx & 15) * 4) = vreg[r];
    }

    asm volatile("s_waitcnt lgkmcnt(0)" ::: "memory");
    __builtin_amdgcn_s_barrier();

    // ---- O = P V : 8 rows x 4 cols per thread (128 x 64 output)
    float o[8][4];
#pragma unroll
    for (int i = 0; i < 8; ++i)
#pragma unroll
        for (int j = 0; j < 4; ++j) o[i][j] = 0.f;

    for (int k = 0; k < 128; ++k) {
        float4 bF = *(const float4*)(sV + k * 64 + tx * 4);
#pragma unroll
        for (int i = 0; i < 8; ++i) {
            const float a = sS[(ty * 8 + i) * 129 + k];   // 16-lane broadcast
#pragma unroll
            for (int j = 0; j < 4; ++j) o[i][j] += a * ((const float*)&bF)[j];
        }
    }

    // in-place write over the Q slice of this (bl, h)
#pragma unroll
    for (int i = 0; i < 8; ++i) {
        const int row = ty * 8 + i;
        float4 ov = {o[i][0], o[i][1], o[i][2], o[i][3]};
        *(float4*)(qkv_out + (size_t)(bl * 128 + row) * 1536 + h * 64 + tx * 4) = ov;
    }
}

// ---------------------------------------------------------------------------
extern "C" void kernel_launch(void* const* d_in, const int* in_sizes, int n_in,
                              void* d_out, int out_size, void* d_ws, size_t ws_size,
                              hipStream_t stream) {
    const float* x      = (const float*)d_in[0];
    const float* mask   = (const float*)d_in[1];
    const float* w_qkv  = (const float*)d_in[2];   // 512 x 1536 row-major
    const float* b_qkv  = (const float*)d_in[3];
    const float* w_proj = (const float*)d_in[4];   // 512 x 512 row-major
    const float* b_proj = (const float*)d_in[5];
    const float* btab   = (const float*)d_in[6];
    float* out = (float*)d_out;

    float* qkv_ws = (float*)d_ws;

    // Slab over windows if ws_size can't hold the full qkv (805 MB)
    int nslab = 1;
    while (nslab < 32 && (size_t)(131072 / nslab) * 1536 * 4 > ws_size) nslab <<= 1;
    const int Ms  = 131072 / nslab;   // rows per slab
    const int Wsl = 1024 / nslab;     // windows per slab

    for (int s = 0; s < nslab; ++s) {
        const float* xs = x + (size_t)s * Ms * 512;
        float* outs = out + (size_t)s * Ms * 512;

        gemm_f32<<<dim3(12, Ms / 128), 256, 0, stream>>>(
            xs, 512, w_qkv, b_qkv, qkv_ws, Ms, 1536, 512);

        attn_f32<<<Wsl * 8, 256, 0, stream>>>(
            qkv_ws, qkv_ws, mask, btab, s * Wsl);

        gemm_f32<<<dim3(4, Ms / 128), 256, 0, stream>>>(
            qkv_ws, 1536, w_proj, b_proj, outs, Ms, 512, 512);
    }
}

// Round 2
// 2262.731 us; speedup vs baseline: 2.0879x; 2.0879x over previous
//
#include <hip/hip_runtime.h>
#include <stdint.h>

// WindowAttention1D. v3: GEMMs moved to split-bf16 3-product MFMA
// (a=a_hi+a_lo bf16; a*b ~= ah*bh + ah*bl + al*bh, fp32 accum). Residual
// ~2^-16 relative of ~0.5-scale intermediates -> ~1e-4 abs output error,
// threshold 2.1e-3, current margin absmax 4.9e-4. 3x bf16 MFMA work =
// 618 GF for QKV -> 248us floor at 2.4 PF vs 1.31ms fp32-vector floor.
// Weights pre-split+transposed once per launch ([N][K] bf16 hi/lo).
// A (fp32, huge) split in-registers during LDS staging.
// GEMM: m97-style 128x128 tile, BK=32, 4 waves 2x2 (64x64/wave),
// 16x16x32 MFMA, single-buffered 2-barrier (v2 lesson: dbuf killed
// occupancy 34->12%, VALUBusy 76->53). Keep v2's wins: XCD swizzle
// (FETCH 1.22->0.75GB), bank-conflict-free patterns (2.8e8->2.5e7).
// Attention: fp32 v2 verbatim (it improved ~480us).

typedef __attribute__((ext_vector_type(8))) short short8;
typedef __attribute__((ext_vector_type(4))) float f32x4;

__device__ __forceinline__ ushort f2bf(float f) {           // RNE fp32->bf16 bits
    uint u = __float_as_uint(f);
    return (ushort)((u + 0x7FFFu + ((u >> 16) & 1u)) >> 16);
}
__device__ __forceinline__ float bf2f(ushort h) {
    return __uint_as_float((uint)h << 16);
}

#define SAT_LD 132   // attn fp32 transposed-tile stride (v2)

// ---------------------------------------------------------------------------
// One-time: W[K][N] fp32 -> WT_hi/WT_lo [N][K] bf16 (split + transpose)
// ---------------------------------------------------------------------------
__global__ __launch_bounds__(256) void split_transpose(
    const float* __restrict__ W, short* __restrict__ Th, short* __restrict__ Tl,
    int K, int N)
{
    __shared__ float sT[64 * 65];
    const int tid = threadIdx.x;
    const long k0 = (long)blockIdx.y * 64;
    const long n0 = (long)blockIdx.x * 64;
    {
        const int kk = tid >> 2;
        const int nq = (tid & 3) * 16;
        const float* wp = W + (k0 + kk) * N + n0 + nq;
        float* dst = sT + kk * 65 + nq;
#pragma unroll
        for (int q = 0; q < 4; ++q) {
            float4 v = *(const float4*)(wp + q * 4);
            dst[q * 4 + 0] = v.x; dst[q * 4 + 1] = v.y;
            dst[q * 4 + 2] = v.z; dst[q * 4 + 3] = v.w;
        }
    }
    __syncthreads();
    const int nn = tid >> 2;
    const int kq = (tid & 3) * 16;
    union { short s[8]; float4 v; } h0, h1, l0, l1;
#pragma unroll
    for (int j = 0; j < 16; ++j) {
        float f = sT[(kq + j) * 65 + nn];
        ushort hb = f2bf(f);
        ushort lb = f2bf(f - bf2f(hb));
        if (j < 8) { h0.s[j] = (short)hb;     l0.s[j] = (short)lb; }
        else       { h1.s[j - 8] = (short)hb; l1.s[j - 8] = (short)lb; }
    }
    const long off = (n0 + nn) * K + k0 + kq;
    *(float4*)(Th + off)     = h0.v;
    *(float4*)(Th + off + 8) = h1.v;
    *(float4*)(Tl + off)     = l0.v;
    *(float4*)(Tl + off + 8) = l1.v;
}

// ---------------------------------------------------------------------------
// C[M x N] = A[M x K fp32 (lda)] @ B + bias, B given pre-split as
// BTh/BTl [N][K] bf16. 128x128 tile, BK=32, 256 thr = 4 waves (2x2),
// wave tile 64x64 = 4x4 frags of 16x16, mfma_f32_16x16x32_bf16 x3/product.
// ---------------------------------------------------------------------------
__global__ __launch_bounds__(256) void gemm_split3(
    const float* __restrict__ A, int lda,
    const short* __restrict__ BTh, const short* __restrict__ BTl,
    const float* __restrict__ bias,
    float* __restrict__ C,
    int M, int N, int K)
{
    // [128 rows][32 k bf16 + 8 pad] = 80B stride, 10KB each, 40KB total
    __shared__ __attribute__((aligned(16))) short sAh[128 * 40];
    __shared__ __attribute__((aligned(16))) short sAl[128 * 40];
    __shared__ __attribute__((aligned(16))) short sBh[128 * 40];
    __shared__ __attribute__((aligned(16))) short sBl[128 * 40];

    const int tid  = threadIdx.x;
    const int lane = tid & 63;
    const int wid  = tid >> 6;
    const int wm   = wid >> 1;
    const int wn   = wid & 1;

    // XCD-chunked bijective swizzle (nwg % 8 == 0 for all our grids)
    int bid = blockIdx.y * gridDim.x + blockIdx.x;
    bid = (bid & 7) * (int)((gridDim.x * gridDim.y) >> 3) + (bid >> 3);
    const long m0 = (long)(bid / (int)gridDim.x) * 128;
    const long n0 = (long)(bid % (int)gridDim.x) * 128;

    // staging assignment: A: thread -> (row tid>>1, 16-col half (tid&1)*16)
    //                     B: thread -> (row tid&127, hi/lo array tid>>7)
    const int ar = tid >> 1;
    const int ac = (tid & 1) * 16;
    const float* Ap = A + (m0 + ar) * (long)lda + ac;
    const int br = tid & 127;
    const short* Bp = ((tid & 128) ? BTl : BTh) + (n0 + br) * (long)K;
    short* sBdst = (tid & 128) ? sBl : sBh;

    f32x4 acc[4][4];
#pragma unroll
    for (int i = 0; i < 4; ++i)
#pragma unroll
        for (int j = 0; j < 4; ++j) acc[i][j] = (f32x4){0.f, 0.f, 0.f, 0.f};

    const int l15 = lane & 15;
    const int kq  = (lane >> 4) * 8;     // contiguous-8 k per lane

    for (int k0 = 0; k0 < K; k0 += 32) {
        // ---- stage A (fp32 load -> RNE split -> bf16 hi/lo in LDS)
        float4 a0 = *(const float4*)(Ap + k0);
        float4 a1 = *(const float4*)(Ap + k0 + 4);
        float4 a2 = *(const float4*)(Ap + k0 + 8);
        float4 a3 = *(const float4*)(Ap + k0 + 12);
        // ---- stage B (already bf16, straight 64B copy)
        float4 b0 = *(const float4*)(Bp + k0);
        float4 b1 = *(const float4*)(Bp + k0 + 8);
        float4 b2 = *(const float4*)(Bp + k0 + 16);
        float4 b3 = *(const float4*)(Bp + k0 + 24);

        const float fa[16] = {a0.x, a0.y, a0.z, a0.w, a1.x, a1.y, a1.z, a1.w,
                              a2.x, a2.y, a2.z, a2.w, a3.x, a3.y, a3.z, a3.w};
        union { short s[8]; float4 v; } h0, h1, q0, q1;
#pragma unroll
        for (int e = 0; e < 8; ++e) {
            ushort hb = f2bf(fa[e]);
            h0.s[e] = (short)hb;
            q0.s[e] = (short)f2bf(fa[e] - bf2f(hb));
        }
#pragma unroll
        for (int e = 0; e < 8; ++e) {
            ushort hb = f2bf(fa[8 + e]);
            h1.s[e] = (short)hb;
            q1.s[e] = (short)f2bf(fa[8 + e] - bf2f(hb));
        }
        {
            short* pa = sAh + ar * 40 + ac;
            *(float4*)(pa)     = h0.v;
            *(float4*)(pa + 8) = h1.v;
            short* pl = sAl + ar * 40 + ac;
            *(float4*)(pl)     = q0.v;
            *(float4*)(pl + 8) = q1.v;
            short* pb = sBdst + br * 40;
            *(float4*)(pb)      = b0;
            *(float4*)(pb + 8)  = b1;
            *(float4*)(pb + 16) = b2;
            *(float4*)(pb + 24) = b3;
        }
        __syncthreads();

        // ---- fragments + 48 MFMA (4m x 4n x 3 products)
        short8 afh[4], afl[4];
#pragma unroll
        for (int mt = 0; mt < 4; ++mt) {
            const int ro = (wm * 64 + mt * 16 + l15) * 40 + kq;
            afh[mt] = *(const short8*)(sAh + ro);
            afl[mt] = *(const short8*)(sAl + ro);
        }
#pragma unroll
        for (int nt = 0; nt < 4; ++nt) {
            const int ro = (wn * 64 + nt * 16 + l15) * 40 + kq;
            short8 bfh = *(const short8*)(sBh + ro);
            short8 bfl = *(const short8*)(sBl + ro);
#pragma unroll
            for (int mt = 0; mt < 4; ++mt) {
                acc[mt][nt] = __builtin_amdgcn_mfma_f32_16x16x32_bf16(
                    afh[mt], bfh, acc[mt][nt], 0, 0, 0);
                acc[mt][nt] = __builtin_amdgcn_mfma_f32_16x16x32_bf16(
                    afh[mt], bfl, acc[mt][nt], 0, 0, 0);
                acc[mt][nt] = __builtin_amdgcn_mfma_f32_16x16x32_bf16(
                    afl[mt], bfh, acc[mt][nt], 0, 0, 0);
            }
        }
        __syncthreads();
    }

    // ---- epilogue: C/D layout col=lane&15, row=(lane>>4)*4+reg (m89-verified)
    const int lq4 = (lane >> 4) * 4;
#pragma unroll
    for (int nt = 0; nt < 4; ++nt) {
        const long col = n0 + wn * 64 + nt * 16 + l15;
        const float bs = bias[col];
#pragma unroll
        for (int mt = 0; mt < 4; ++mt) {
            const long rbase = m0 + wm * 64 + mt * 16 + lq4;
            float* cp = C + rbase * (long)N + col;
#pragma unroll
            for (int r = 0; r < 4; ++r)
                cp[(long)r * N] = acc[mt][nt][r] + bs;
        }
    }
}

// ---------------------------------------------------------------------------
// Fused window attention, fp32 (v2 verbatim). One block per (window, head).
// ---------------------------------------------------------------------------
__global__ __launch_bounds__(256) void attn_f32(
    const float* __restrict__ qkv,
    float* __restrict__ qkv_out,
    const float* __restrict__ mask,
    const float* __restrict__ bt,
    int b_base)
{
    __shared__ __attribute__((aligned(16))) float sQT[64 * SAT_LD]; // later: sV
    __shared__ __attribute__((aligned(16))) float sKT[64 * SAT_LD];
    __shared__ __attribute__((aligned(16))) float sS[128 * 129];
    __shared__ float sBias[256];

    const int tid = threadIdx.x;
    int bh = blockIdx.x;
    bh = (bh & 7) * ((int)(gridDim.x) >> 3) + (bh >> 3);   // XCD swizzle
    const int bl = bh >> 3;
    const int h  = bh & 7;
    const int widx = (b_base + bl) & 63;
    const float* base = qkv + (size_t)bl * 128 * 1536 + h * 64;

    {
        const int t_st  = tid & 15;
        const int d4_st = (tid >> 4) * 4;
#pragma unroll
        for (int r = 0; r < 8; ++r) {
            const int t = r * 16 + t_st;
            float4 q = *(const float4*)(base + (size_t)t * 1536 + d4_st);
            float4 k = *(const float4*)(base + (size_t)t * 1536 + 512 + d4_st);
#pragma unroll
            for (int j = 0; j < 4; ++j) {
                sQT[(d4_st + j) * SAT_LD + t] = ((const float*)&q)[j];
                sKT[(d4_st + j) * SAT_LD + t] = ((const float*)&k)[j];
            }
        }
    }
    if (tid < 255) sBias[tid] = bt[tid * 8 + h];
    __syncthreads();

    const int tx = tid & 15;
    const int ty = tid >> 4;

    float acc[8][8];
#pragma unroll
    for (int i = 0; i < 8; ++i)
#pragma unroll
        for (int j = 0; j < 8; ++j) acc[i][j] = 0.f;

    for (int kk = 0; kk < 64; ++kk) {
        float av[8], bv[8];
        *(float4*)&av[0] = *(const float4*)(sQT + kk * SAT_LD + ty * 8);
        *(float4*)&av[4] = *(const float4*)(sQT + kk * SAT_LD + ty * 8 + 4);
        *(float4*)&bv[0] = *(const float4*)(sKT + kk * SAT_LD + tx * 4);
        *(float4*)&bv[4] = *(const float4*)(sKT + kk * SAT_LD + 64 + tx * 4);
#pragma unroll
        for (int i = 0; i < 8; ++i)
#pragma unroll
            for (int j = 0; j < 8; ++j)
                acc[i][j] += av[i] * bv[j];
    }

    const float* maskp = mask + (size_t)widx * 16384;
#pragma unroll
    for (int i = 0; i < 8; ++i) {
        const int row = ty * 8 + i;
#pragma unroll
        for (int j = 0; j < 4; ++j) {
            const int c0 = tx * 4 + j;
            const int c1 = 64 + tx * 4 + j;
            sS[row * 129 + c0] = acc[i][j]     * 0.125f + sBias[c0 - row + 127]
                               + maskp[row * 128 + c0];
            sS[row * 129 + c1] = acc[i][j + 4] * 0.125f + sBias[c1 - row + 127]
                               + maskp[row * 128 + c1];
        }
    }

    float4 vreg[8];
    {
        const float* vbase = base + 1024;
#pragma unroll
        for (int r = 0; r < 8; ++r) {
            const int idx = tid + r * 256;
            vreg[r] = *(const float4*)(vbase + (size_t)(idx >> 4) * 1536
                                       + (idx & 15) * 4);
        }
    }

    asm volatile("s_waitcnt lgkmcnt(0)" ::: "memory");
    __builtin_amdgcn_s_barrier();

    {
        const int row = tid >> 1;
        const int hc  = (tid & 1) * 64;
        float* rp = sS + row * 129 + hc;
        float mx = -3.4e38f;
        for (int c = 0; c < 64; ++c) mx = fmaxf(mx, rp[c]);
        mx = fmaxf(mx, __shfl_xor(mx, 1));
        float sum = 0.f;
        for (int c = 0; c < 64; ++c) {
            float e = __expf(rp[c] - mx);
            rp[c] = e;
            sum += e;
        }
        sum += __shfl_xor(sum, 1);
        const float rl = 1.0f / sum;
        for (int c = 0; c < 64; ++c) rp[c] *= rl;
    }

    float* sV = sQT;
#pragma unroll
    for (int r = 0; r < 8; ++r) {
        const int idx = tid + r * 256;
        *(float4*)(sV + (idx >> 4) * 64 + (idx & 15) * 4) = vreg[r];
    }

    asm volatile("s_waitcnt lgkmcnt(0)" ::: "memory");
    __builtin_amdgcn_s_barrier();

    float o[8][4];
#pragma unroll
    for (int i = 0; i < 8; ++i)
#pragma unroll
        for (int j = 0; j < 4; ++j) o[i][j] = 0.f;

    for (int k = 0; k < 128; ++k) {
        float4 bF = *(const float4*)(sV + k * 64 + tx * 4);
#pragma unroll
        for (int i = 0; i < 8; ++i) {
            const float a = sS[(ty * 8 + i) * 129 + k];
#pragma unroll
            for (int j = 0; j < 4; ++j) o[i][j] += a * ((const float*)&bF)[j];
        }
    }

#pragma unroll
    for (int i = 0; i < 8; ++i) {
        const int row = ty * 8 + i;
        float4 ov = {o[i][0], o[i][1], o[i][2], o[i][3]};
        *(float4*)(qkv_out + (size_t)(bl * 128 + row) * 1536 + h * 64 + tx * 4) = ov;
    }
}

// ---------------------------------------------------------------------------
extern "C" void kernel_launch(void* const* d_in, const int* in_sizes, int n_in,
                              void* d_out, int out_size, void* d_ws, size_t ws_size,
                              hipStream_t stream) {
    const float* x      = (const float*)d_in[0];
    const float* mask   = (const float*)d_in[1];
    const float* w_qkv  = (const float*)d_in[2];   // 512 x 1536 row-major
    const float* b_qkv  = (const float*)d_in[3];
    const float* w_proj = (const float*)d_in[4];   // 512 x 512 row-major
    const float* b_proj = (const float*)d_in[5];
    const float* btab   = (const float*)d_in[6];
    float* out = (float*)d_out;

    // workspace: [wqT_hi | wqT_lo | wpT_hi | wpT_lo | qkv slab]
    const size_t wq = 1536 * 512, wp = 512 * 512;
    short* wqT_hi = (short*)d_ws;
    short* wqT_lo = wqT_hi + wq;
    short* wpT_hi = wqT_lo + wq;
    short* wpT_lo = wpT_hi + wp;
    const size_t woff = ((2 * wq + 2 * wp) * sizeof(short) + 255) & ~(size_t)255;
    float* qkv_ws = (float*)((char*)d_ws + woff);
    const size_t avail = ws_size - woff;

    // one-time weight split+transpose (amortized over all m-blocks)
    split_transpose<<<dim3(1536 / 64, 512 / 64), 256, 0, stream>>>(
        w_qkv, wqT_hi, wqT_lo, 512, 1536);
    split_transpose<<<dim3(512 / 64, 512 / 64), 256, 0, stream>>>(
        w_proj, wpT_hi, wpT_lo, 512, 512);

    int nslab = 1;
    while (nslab < 32 && (size_t)(131072 / nslab) * 1536 * 4 > avail) nslab <<= 1;
    const int Ms  = 131072 / nslab;   // rows per slab
    const int Wsl = 1024 / nslab;     // windows per slab

    for (int s = 0; s < nslab; ++s) {
        const float* xs = x + (size_t)s * Ms * 512;
        float* outs = out + (size_t)s * Ms * 512;

        gemm_split3<<<dim3(12, Ms / 128), 256, 0, stream>>>(
            xs, 512, wqT_hi, wqT_lo, b_qkv, qkv_ws, Ms, 1536, 512);

        attn_f32<<<Wsl * 8, 256, 0, stream>>>(
            qkv_ws, qkv_ws, mask, btab, s * Wsl);

        gemm_split3<<<dim3(4, Ms / 128), 256, 0, stream>>>(
            qkv_ws, 1536, wpT_hi, wpT_lo, b_proj, outs, Ms, 512, 512);
    }
}